// Round 3
// baseline (173.962 us; speedup 1.0000x reference)
//
#include <hip/hip_runtime.h>
#include <hip/hip_bf16.h>

// Shapes (fixed by reference): b=2, h=8, t=8192, dh=128
#define T_SEQ   8192
#define DH      128
#define NBH     16
#define NBUCK   128
#define BSZ     64
#define EPSF    1e-6f

// 16B-granular XOR swizzle (keeps b128 reads contiguous)
#define SWZ(r) (((((r) & 7) ^ (((r) >> 3) & 7))) << 3)

typedef __attribute__((ext_vector_type(8))) __bf16 bf16x8;
typedef __attribute__((ext_vector_type(4))) float  f32x4;

static __device__ __forceinline__ unsigned short f2bf(float f) {
  __bf16 h = (__bf16)f;
  return __builtin_bit_cast(unsigned short, h);
}

// ---------------------------------------------------------------------------
// Kernel 1: bucket sums. grid (128, 16, 2[q|k]), 256 threads. Pure streaming.
// ---------------------------------------------------------------------------
__global__ __launch_bounds__(256) void k_bsum(
    const float* __restrict__ q, const float* __restrict__ k,
    float* __restrict__ x) {
  const int u = blockIdx.x, bh = blockIdx.y, which = blockIdx.z;
  const int t = threadIdx.x;
  const int c4g = t & 31;
  const int r0  = (t >> 5) << 3;
  const float* src = which ? k : q;
  const float* p = src + ((size_t)bh * T_SEQ + (size_t)u * BSZ + r0) * DH + c4g * 4;
  float4 acc = {0.f, 0.f, 0.f, 0.f};
  #pragma unroll
  for (int r = 0; r < 8; r++) {
    float4 vv = *(const float4*)(p + (size_t)r * DH);
    acc.x += vv.x; acc.y += vv.y; acc.z += vv.z; acc.w += vv.w;
  }
  __shared__ float4 xr[8][32];
  xr[t >> 5][c4g] = acc;
  __syncthreads();
  if (t < 32) {
    float4 s4 = xr[0][t];
    #pragma unroll
    for (int j = 1; j < 8; j++) {
      float4 o = xr[j][t];
      s4.x += o.x; s4.y += o.y; s4.z += o.z; s4.w += o.w;
    }
    *(float4*)(x + ((size_t)bh * NBUCK + u) * 256 + which * 128 + t * 4) = s4;
  }
}

// ---------------------------------------------------------------------------
// Kernel 2: sortnet GEMM + relu + gumbel-log. grid (32, 16), 128 threads.
// ---------------------------------------------------------------------------
__global__ __launch_bounds__(128) void k_sortgemm(
    const float* __restrict__ x, const float* __restrict__ W,
    const float* __restrict__ ug, float* __restrict__ rbuf) {
  const int u0 = blockIdx.x * 4, bh = blockIdx.y;
  const int v = threadIdx.x;
  __shared__ float xs[4][256];
  for (int i = v; i < 1024; i += 128)
    xs[i >> 8][i & 255] = x[((size_t)bh * NBUCK + u0 + (i >> 8)) * 256 + (i & 255)];
  __syncthreads();
  const float* Wp = W + (size_t)(bh & 7) * 256 * NBUCK + v;
  float acc0 = 0.f, acc1 = 0.f, acc2 = 0.f, acc3 = 0.f;
  #pragma unroll 16
  for (int e = 0; e < 256; e++) {
    float we = Wp[(size_t)e * NBUCK];
    acc0 += xs[0][e] * we;
    acc1 += xs[1][e] * we;
    acc2 += xs[2][e] * we;
    acc3 += xs[3][e] * we;
  }
  float accs[4] = {acc0, acc1, acc2, acc3};
  #pragma unroll
  for (int j = 0; j < 4; j++) {
    float R = fmaxf(accs[j], 0.f) + EPSF;
    float gu = ug[((size_t)bh * NBUCK + u0 + j) * NBUCK + v] + EPSF;
    float g = -logf(-logf(gu) + EPSF);
    rbuf[((size_t)bh * NBUCK + u0 + j) * NBUCK + v] = (logf(R) + g) * (1.f / 0.75f);
  }
}

// ---------------------------------------------------------------------------
// Kernel 3: sinkhorn, register-resident. grid 16, 512 threads.
// Thread t owns: row (t>>2), col-quarter (t&3) slice (32 f32 in regs) AND
// col (t>>2), row-quarter slice. Reduce over the 4-lane group via shfl_xor.
// ca/ra broadcast through LDS. rl kept in LDS only for the argmax tail.
// ---------------------------------------------------------------------------
__global__ __launch_bounds__(512, 1) void k_sinkhorn(
    const float* __restrict__ rbuf, int* __restrict__ idxb, float* __restrict__ sb) {
  const int bh = blockIdx.x;
  const int t  = threadIdx.x;
  const int own = t >> 2;     // row (phase A) / col (phase B), 0..127
  const int qq  = t & 3;      // quarter
  __shared__ float rl[128 * 129];
  __shared__ float ca[128], ra[128];

  const float* rb = rbuf + (size_t)bh * (NBUCK * NBUCK);
  for (int i = t; i < NBUCK * NBUCK; i += 512)
    rl[(i >> 7) * 129 + (i & 127)] = rb[i];
  if (t < 128) ca[t] = 0.f;
  __syncthreads();

  float rowv[32], colv[32];
  #pragma unroll
  for (int i4 = 0; i4 < 8; i4++) {
    float4 vv = *(const float4*)(&rl[own * 129 + qq * 32 + i4 * 4]);
    rowv[i4 * 4 + 0] = vv.x; rowv[i4 * 4 + 1] = vv.y;
    rowv[i4 * 4 + 2] = vv.z; rowv[i4 * 4 + 3] = vv.w;
  }
  #pragma unroll
  for (int i = 0; i < 32; i++) colv[i] = rl[(qq * 32 + i) * 129 + own];

  for (int iter = 0; iter < 7; iter++) {
    // row phase: ra[u] = -LSE_v(r0[u][v] + ca[v])
    {
      float vals[32];
      float m = -1e30f;
      #pragma unroll
      for (int i4 = 0; i4 < 8; i4++) {
        float4 cc = *(const float4*)(&ca[qq * 32 + i4 * 4]);
        vals[i4 * 4 + 0] = rowv[i4 * 4 + 0] + cc.x;
        vals[i4 * 4 + 1] = rowv[i4 * 4 + 1] + cc.y;
        vals[i4 * 4 + 2] = rowv[i4 * 4 + 2] + cc.z;
        vals[i4 * 4 + 3] = rowv[i4 * 4 + 3] + cc.w;
      }
      #pragma unroll
      for (int i = 0; i < 32; i++) m = fmaxf(m, vals[i]);
      m = fmaxf(m, __shfl_xor(m, 1));
      m = fmaxf(m, __shfl_xor(m, 2));
      float s0 = 0.f, s1 = 0.f, s2 = 0.f, s3 = 0.f;
      #pragma unroll
      for (int i = 0; i < 8; i++) {
        s0 += __expf(vals[i * 4 + 0] - m);
        s1 += __expf(vals[i * 4 + 1] - m);
        s2 += __expf(vals[i * 4 + 2] - m);
        s3 += __expf(vals[i * 4 + 3] - m);
      }
      float ss = (s0 + s1) + (s2 + s3);
      ss += __shfl_xor(ss, 1);
      ss += __shfl_xor(ss, 2);
      if (qq == 0) ra[own] = -(m + logf(ss));
    }
    __syncthreads();
    // col phase: ca[v] = -LSE_u(r0[u][v] + ra[u])
    {
      float vals[32];
      float m = -1e30f;
      #pragma unroll
      for (int i4 = 0; i4 < 8; i4++) {
        float4 rr = *(const float4*)(&ra[qq * 32 + i4 * 4]);
        vals[i4 * 4 + 0] = colv[i4 * 4 + 0] + rr.x;
        vals[i4 * 4 + 1] = colv[i4 * 4 + 1] + rr.y;
        vals[i4 * 4 + 2] = colv[i4 * 4 + 2] + rr.z;
        vals[i4 * 4 + 3] = colv[i4 * 4 + 3] + rr.w;
      }
      #pragma unroll
      for (int i = 0; i < 32; i++) m = fmaxf(m, vals[i]);
      m = fmaxf(m, __shfl_xor(m, 1));
      m = fmaxf(m, __shfl_xor(m, 2));
      float s0 = 0.f, s1 = 0.f, s2 = 0.f, s3 = 0.f;
      #pragma unroll
      for (int i = 0; i < 8; i++) {
        s0 += __expf(vals[i * 4 + 0] - m);
        s1 += __expf(vals[i * 4 + 1] - m);
        s2 += __expf(vals[i * 4 + 2] - m);
        s3 += __expf(vals[i * 4 + 3] - m);
      }
      float ss = (s0 + s1) + (s2 + s3);
      ss += __shfl_xor(ss, 1);
      ss += __shfl_xor(ss, 2);
      if (qq == 0) ca[own] = -(m + logf(ss));
    }
    __syncthreads();
  }

  // per-row argmax over v of r0 + ca[v] (first index on tie, like jnp.argmax)
  {
    float best = -1e30f; int bi = qq * 32;
    #pragma unroll
    for (int i = 0; i < 32; i++) {
      float val = rowv[i] + ca[qq * 32 + i];
      if (val > best) { best = val; bi = qq * 32 + i; }
    }
    #pragma unroll
    for (int d = 1; d < 4; d <<= 1) {
      float ob = __shfl_xor(best, d);
      int   oi = __shfl_xor(bi, d);
      if (ob > best || (ob == best && oi < bi)) { best = ob; bi = oi; }
    }
    if (qq == 0) {
      idxb[bh * NBUCK + own] = bi;
      sb[bh * NBUCK + own]   = expf(rl[own * 129 + bi] + ra[own] + ca[bi]);
    }
  }
}

// ---------------------------------------------------------------------------
// Kernel 4: per-bucket attention. grid (128,16), 256 threads (4 waves).
// 32 KB LDS + VGPR<=102 -> 5 blocks/CU. Load order: K batch, Q batch, V1
// batch; V2 issued after V1 stores (hides under PV1). setprio around MFMA.
// ---------------------------------------------------------------------------
__global__ __launch_bounds__(256, 5) void k_attn(
    const float* __restrict__ q, const float* __restrict__ k, const float* __restrict__ v,
    const int* __restrict__ idxb, const float* __restrict__ sb, float* __restrict__ out) {
  const int u  = blockIdx.x;
  const int bh = blockIdx.y;
  const int t  = threadIdx.x;
  const int lane = t & 63;
  const int w  = t >> 6;
  const int l15 = lane & 15;
  const int lgp = lane >> 4;

  __shared__ uint4 smem4[2048];   // 32 KB
  unsigned short* sm = (unsigned short*)smem4;
  #define VOFF 8192

  const int   vidx = idxb[bh * NBUCK + u];
  const float sval = sb[bh * NBUCK + u];
  const size_t hb = (size_t)bh * (T_SEQ * DH);
  const float* qg = q + hb;
  const float* kg = k + hb;
  const float* vg = v + hb;

  // ---- issue K loads (16 float4, need earliest) ----
  float4 kr[16];
  #pragma unroll
  for (int it = 0; it < 16; it++) {
    int i = it * 256 + t;
    int row = i >> 5;
    int c4 = (i & 31) << 2;
    int grow = (row < 64) ? (vidx * BSZ + row) : (u * BSZ + (row - 64));
    kr[it] = *(const float4*)(kg + (size_t)grow * DH + c4);
  }
  // ---- issue Q loads (8 float4, needed right after B1) ----
  float4 qf[8];
  {
    int qrow = u * BSZ + w * 16 + l15;
    const float* qp = qg + (size_t)qrow * DH + lgp * 8;
    #pragma unroll
    for (int kk = 0; kk < 4; kk++) {
      qf[kk * 2 + 0] = *(const float4*)(qp + kk * 32);
      qf[kk * 2 + 1] = *(const float4*)(qp + kk * 32 + 4);
    }
  }
  // ---- K -> LDS (cvt + swizzled stores) ----
  #pragma unroll
  for (int it = 0; it < 16; it++) {
    int i = it * 256 + t;
    int row = i >> 5;
    int c4 = (i & 31) << 2;
    float4 val = kr[it];
    ushort4 hh;
    hh.x = f2bf(val.x); hh.y = f2bf(val.y); hh.z = f2bf(val.z); hh.w = f2bf(val.w);
    *(ushort4*)(sm + (((row * 128 + c4) ^ SWZ(row)))) = hh;
  }
  // ---- issue V half-1 loads (consumed after B2) ----
  float4 vpre1[8];
  #pragma unroll
  for (int it = 0; it < 8; it++) {
    int i = it * 256 + t;
    int d0 = (i & 31) << 2;
    int j  = i >> 5;
    vpre1[it] = *(const float4*)(vg + (size_t)(vidx * BSZ + j) * DH + d0);
  }
  __syncthreads();   // B1: K staged

  // ---- Q fragments ----
  bf16x8 aQ[4];
  #pragma unroll
  for (int kk = 0; kk < 4; kk++) {
    float4 v0 = qf[kk * 2 + 0];
    float4 v1 = qf[kk * 2 + 1];
    bf16x8 f;
    f[0] = (__bf16)v0.x; f[1] = (__bf16)v0.y; f[2] = (__bf16)v0.z; f[3] = (__bf16)v0.w;
    f[4] = (__bf16)v1.x; f[5] = (__bf16)v1.y; f[6] = (__bf16)v1.z; f[7] = (__bf16)v1.w;
    aQ[kk] = f;
  }

  // ---- S = Q K^T ----
  f32x4 accS[8];
  __builtin_amdgcn_s_setprio(1);
  #pragma unroll
  for (int n = 0; n < 8; n++) {
    f32x4 acc = {0.f, 0.f, 0.f, 0.f};
    #pragma unroll
    for (int kk = 0; kk < 4; kk++) {
      int row = n * 16 + l15;
      int c0 = lgp * 8 + kk * 32;
      bf16x8 bK = *(const bf16x8*)(sm + ((row * 128 + c0) ^ SWZ(row)));
      acc = __builtin_amdgcn_mfma_f32_16x16x32_bf16(aQ[kk], bK, acc, 0, 0, 0);
    }
    accS[n] = acc;
  }
  __builtin_amdgcn_s_setprio(0);

  // ---- softmax per row ----
  float pval[8][4];
  float lsum[4];
  #pragma unroll
  for (int r = 0; r < 4; r++) {
    float mm = -1e30f;
    #pragma unroll
    for (int n = 0; n < 8; n++) {
      float lg2 = accS[n][r] * 0.03125f * (n < 4 ? sval : 1.0f);
      pval[n][r] = lg2;
      mm = fmaxf(mm, lg2);
    }
    mm = fmaxf(mm, __shfl_xor(mm, 1));
    mm = fmaxf(mm, __shfl_xor(mm, 2));
    mm = fmaxf(mm, __shfl_xor(mm, 4));
    mm = fmaxf(mm, __shfl_xor(mm, 8));
    float ss = 0.f;
    #pragma unroll
    for (int n = 0; n < 8; n++) {
      float p = __expf(pval[n][r] - mm);
      ss += p;
      pval[n][r] = p * (n < 4 ? sval : 1.0f);
    }
    ss += __shfl_xor(ss, 1);
    ss += __shfl_xor(ss, 2);
    ss += __shfl_xor(ss, 4);
    ss += __shfl_xor(ss, 8);
    lsum[r] = ss;
  }

  __syncthreads();   // B2: all waves done reading K

  // ---- write P (own wave rows) into [0,8192) ----
  #pragma unroll
  for (int n = 0; n < 8; n++) {
    #pragma unroll
    for (int r = 0; r < 4; r++) {
      int prow = w * 16 + lgp * 4 + r;
      int pcol = n * 16 + l15;
      sm[(prow * 128 + pcol) ^ SWZ(prow)] = f2bf(pval[n][r]);
    }
  }
  // ---- V half-1 regs -> LDS ----
  #pragma unroll
  for (int it = 0; it < 8; it++) {
    int i = it * 256 + t;
    int d0 = (i & 31) << 2;
    int j  = i >> 5;
    float4 val = vpre1[it];
    sm[VOFF + (((d0 + 0) * 64 + j) ^ SWZ(d0 + 0))] = f2bf(val.x);
    sm[VOFF + (((d0 + 1) * 64 + j) ^ SWZ(d0 + 1))] = f2bf(val.y);
    sm[VOFF + (((d0 + 2) * 64 + j) ^ SWZ(d0 + 2))] = f2bf(val.z);
    sm[VOFF + (((d0 + 3) * 64 + j) ^ SWZ(d0 + 3))] = f2bf(val.w);
  }
  // ---- issue V half-2 loads (latency hides under PV1) ----
  float4 vpre2[8];
  #pragma unroll
  for (int it = 0; it < 8; it++) {
    int i = it * 256 + t;
    int d0 = (i & 31) << 2;
    int j  = i >> 5;
    vpre2[it] = *(const float4*)(vg + (size_t)(u * BSZ + j) * DH + d0);
  }
  __syncthreads();   // B3: Vh1 + P ready

  // ---- aP fragments ----
  bf16x8 aP[4];
  #pragma unroll
  for (int kk = 0; kk < 4; kk++) {
    int prow = w * 16 + l15;
    int c0 = lgp * 8 + kk * 32;
    aP[kk] = *(const bf16x8*)(sm + ((prow * 128 + c0) ^ SWZ(prow)));
  }

  // ---- PV part 1 (j = 0..63) ----
  f32x4 accO[8];
  __builtin_amdgcn_s_setprio(1);
  #pragma unroll
  for (int n = 0; n < 8; n++) {
    f32x4 acc = {0.f, 0.f, 0.f, 0.f};
    #pragma unroll
    for (int kk = 0; kk < 2; kk++) {
      int d = n * 16 + l15;
      int jj0 = lgp * 8 + kk * 32;
      bf16x8 bV = *(const bf16x8*)(sm + VOFF + ((d * 64 + jj0) ^ SWZ(d)));
      acc = __builtin_amdgcn_mfma_f32_16x16x32_bf16(aP[kk], bV, acc, 0, 0, 0);
    }
    accO[n] = acc;
  }
  __builtin_amdgcn_s_setprio(0);
  __syncthreads();   // B4: done reading Vh1

  // ---- V half-2 regs -> LDS ----
  #pragma unroll
  for (int it = 0; it < 8; it++) {
    int i = it * 256 + t;
    int d0 = (i & 31) << 2;
    int j  = i >> 5;
    float4 val = vpre2[it];
    sm[VOFF + (((d0 + 0) * 64 + j) ^ SWZ(d0 + 0))] = f2bf(val.x);
    sm[VOFF + (((d0 + 1) * 64 + j) ^ SWZ(d0 + 1))] = f2bf(val.y);
    sm[VOFF + (((d0 + 2) * 64 + j) ^ SWZ(d0 + 2))] = f2bf(val.z);
    sm[VOFF + (((d0 + 3) * 64 + j) ^ SWZ(d0 + 3))] = f2bf(val.w);
  }
  __syncthreads();   // B5: Vh2 ready

  float invl[4];
  #pragma unroll
  for (int r = 0; r < 4; r++) invl[r] = 1.0f / lsum[r];

  // ---- PV part 2 (j = 64..127) + store ----
  __builtin_amdgcn_s_setprio(1);
  #pragma unroll
  for (int n = 0; n < 8; n++) {
    f32x4 acc = accO[n];
    #pragma unroll
    for (int kk = 2; kk < 4; kk++) {
      int d = n * 16 + l15;
      int jj0 = lgp * 8 + (kk - 2) * 32;
      bf16x8 bV = *(const bf16x8*)(sm + VOFF + ((d * 64 + jj0) ^ SWZ(d)));
      acc = __builtin_amdgcn_mfma_f32_16x16x32_bf16(aP[kk], bV, acc, 0, 0, 0);
    }
    #pragma unroll
    for (int r = 0; r < 4; r++) {
      int i2 = w * 16 + lgp * 4 + r;
      int d = n * 16 + l15;
      out[((size_t)bh * T_SEQ + (size_t)u * BSZ + i2) * DH + d] = acc[r] * invl[r];
    }
  }
  __builtin_amdgcn_s_setprio(0);
}

// ---------------------------------------------------------------------------
extern "C" void kernel_launch(void* const* d_in, const int* in_sizes, int n_in,
                              void* d_out, int out_size, void* d_ws, size_t ws_size,
                              hipStream_t stream) {
  (void)in_sizes; (void)n_in; (void)out_size; (void)ws_size;
  const float* q  = (const float*)d_in[0];
  const float* k  = (const float*)d_in[1];
  const float* v  = (const float*)d_in[2];
  const float* W  = (const float*)d_in[3];
  const float* ug = (const float*)d_in[4];
  float* out = (float*)d_out;

  float* xbuf = (float*)d_ws;                                  // 2 MB
  float* rbuf = xbuf + (size_t)NBH * NBUCK * 256;              // 1 MB
  int*   idxb = (int*)(rbuf + (size_t)NBH * NBUCK * NBUCK);
  float* sb   = (float*)(idxb + NBH * NBUCK);

  k_bsum    <<<dim3(NBUCK, NBH, 2), 256, 0, stream>>>(q, k, xbuf);
  k_sortgemm<<<dim3(32, NBH),       128, 0, stream>>>(xbuf, W, ug, rbuf);
  k_sinkhorn<<<NBH,                 512, 0, stream>>>(rbuf, idxb, sb);
  k_attn    <<<dim3(NBUCK, NBH),    256, 0, stream>>>(q, k, v, idxb, sb, out);
}

// Round 5
// 113.968 us; speedup vs baseline: 1.5264x; 1.5264x over previous
//
#include <hip/hip_runtime.h>
#include <hip/hip_bf16.h>

// Shapes (fixed by reference): b=2, h=8, t=8192, dh=128
#define T_SEQ   8192
#define DH      128
#define NBH     16
#define NBUCK   128
#define BSZ     64
#define EPSF    1e-6f

// 16B-granular XOR swizzle (keeps b128 reads contiguous)
#define SWZ(r) (((((r) & 7) ^ (((r) >> 3) & 7))) << 3)

typedef __attribute__((ext_vector_type(8))) __bf16 bf16x8;
typedef __attribute__((ext_vector_type(4))) float  f32x4;

static __device__ __forceinline__ unsigned short f2bf(float f) {
  __bf16 h = (__bf16)f;
  return __builtin_bit_cast(unsigned short, h);
}

// ---------------------------------------------------------------------------
// Kernel 1: bucket sums. grid (128, 16, 2[q|k]), 256 threads. Pure streaming.
// ---------------------------------------------------------------------------
__global__ __launch_bounds__(256) void k_bsum(
    const float* __restrict__ q, const float* __restrict__ k,
    float* __restrict__ x) {
  const int u = blockIdx.x, bh = blockIdx.y, which = blockIdx.z;
  const int t = threadIdx.x;
  const int c4g = t & 31;
  const int r0  = (t >> 5) << 3;
  const float* src = which ? k : q;
  const float* p = src + ((size_t)bh * T_SEQ + (size_t)u * BSZ + r0) * DH + c4g * 4;
  float4 acc = {0.f, 0.f, 0.f, 0.f};
  #pragma unroll
  for (int r = 0; r < 8; r++) {
    float4 vv = *(const float4*)(p + (size_t)r * DH);
    acc.x += vv.x; acc.y += vv.y; acc.z += vv.z; acc.w += vv.w;
  }
  __shared__ float4 xr[8][32];
  xr[t >> 5][c4g] = acc;
  __syncthreads();
  if (t < 32) {
    float4 s4 = xr[0][t];
    #pragma unroll
    for (int j = 1; j < 8; j++) {
      float4 o = xr[j][t];
      s4.x += o.x; s4.y += o.y; s4.z += o.z; s4.w += o.w;
    }
    *(float4*)(x + ((size_t)bh * NBUCK + u) * 256 + which * 128 + t * 4) = s4;
  }
}

// ---------------------------------------------------------------------------
// Kernel 2: sortnet GEMM + relu + gumbel-log. grid (32, 16), 128 threads.
// ---------------------------------------------------------------------------
__global__ __launch_bounds__(128) void k_sortgemm(
    const float* __restrict__ x, const float* __restrict__ W,
    const float* __restrict__ ug, float* __restrict__ rbuf) {
  const int u0 = blockIdx.x * 4, bh = blockIdx.y;
  const int v = threadIdx.x;
  __shared__ float xs[4][256];
  for (int i = v; i < 1024; i += 128)
    xs[i >> 8][i & 255] = x[((size_t)bh * NBUCK + u0 + (i >> 8)) * 256 + (i & 255)];
  __syncthreads();
  const float* Wp = W + (size_t)(bh & 7) * 256 * NBUCK + v;
  float acc0 = 0.f, acc1 = 0.f, acc2 = 0.f, acc3 = 0.f;
  #pragma unroll 16
  for (int e = 0; e < 256; e++) {
    float we = Wp[(size_t)e * NBUCK];
    acc0 += xs[0][e] * we;
    acc1 += xs[1][e] * we;
    acc2 += xs[2][e] * we;
    acc3 += xs[3][e] * we;
  }
  float accs[4] = {acc0, acc1, acc2, acc3};
  #pragma unroll
  for (int j = 0; j < 4; j++) {
    float R = fmaxf(accs[j], 0.f) + EPSF;
    float gu = ug[((size_t)bh * NBUCK + u0 + j) * NBUCK + v] + EPSF;
    float g = -logf(-logf(gu) + EPSF);
    rbuf[((size_t)bh * NBUCK + u0 + j) * NBUCK + v] = (logf(R) + g) * (1.f / 0.75f);
  }
}

// ---------------------------------------------------------------------------
// Kernel 3: sinkhorn, register-resident. grid 16, 512 threads.
// ---------------------------------------------------------------------------
__global__ __launch_bounds__(512, 1) void k_sinkhorn(
    const float* __restrict__ rbuf, int* __restrict__ idxb, float* __restrict__ sb) {
  const int bh = blockIdx.x;
  const int t  = threadIdx.x;
  const int own = t >> 2;
  const int qq  = t & 3;
  __shared__ float rl[128 * 129];
  __shared__ float ca[128], ra[128];

  const float* rb = rbuf + (size_t)bh * (NBUCK * NBUCK);
  for (int i = t; i < NBUCK * NBUCK; i += 512)
    rl[(i >> 7) * 129 + (i & 127)] = rb[i];
  if (t < 128) ca[t] = 0.f;
  __syncthreads();

  float rowv[32], colv[32];
  #pragma unroll
  for (int i4 = 0; i4 < 8; i4++) {
    float4 vv = *(const float4*)(&rl[own * 129 + qq * 32 + i4 * 4]);
    rowv[i4 * 4 + 0] = vv.x; rowv[i4 * 4 + 1] = vv.y;
    rowv[i4 * 4 + 2] = vv.z; rowv[i4 * 4 + 3] = vv.w;
  }
  #pragma unroll
  for (int i = 0; i < 32; i++) colv[i] = rl[(qq * 32 + i) * 129 + own];

  for (int iter = 0; iter < 7; iter++) {
    {
      float vals[32];
      float m = -1e30f;
      #pragma unroll
      for (int i4 = 0; i4 < 8; i4++) {
        float4 cc = *(const float4*)(&ca[qq * 32 + i4 * 4]);
        vals[i4 * 4 + 0] = rowv[i4 * 4 + 0] + cc.x;
        vals[i4 * 4 + 1] = rowv[i4 * 4 + 1] + cc.y;
        vals[i4 * 4 + 2] = rowv[i4 * 4 + 2] + cc.z;
        vals[i4 * 4 + 3] = rowv[i4 * 4 + 3] + cc.w;
      }
      #pragma unroll
      for (int i = 0; i < 32; i++) m = fmaxf(m, vals[i]);
      m = fmaxf(m, __shfl_xor(m, 1));
      m = fmaxf(m, __shfl_xor(m, 2));
      float s0 = 0.f, s1 = 0.f, s2 = 0.f, s3 = 0.f;
      #pragma unroll
      for (int i = 0; i < 8; i++) {
        s0 += __expf(vals[i * 4 + 0] - m);
        s1 += __expf(vals[i * 4 + 1] - m);
        s2 += __expf(vals[i * 4 + 2] - m);
        s3 += __expf(vals[i * 4 + 3] - m);
      }
      float ss = (s0 + s1) + (s2 + s3);
      ss += __shfl_xor(ss, 1);
      ss += __shfl_xor(ss, 2);
      if (qq == 0) ra[own] = -(m + logf(ss));
    }
    __syncthreads();
    {
      float vals[32];
      float m = -1e30f;
      #pragma unroll
      for (int i4 = 0; i4 < 8; i4++) {
        float4 rr = *(const float4*)(&ra[qq * 32 + i4 * 4]);
        vals[i4 * 4 + 0] = colv[i4 * 4 + 0] + rr.x;
        vals[i4 * 4 + 1] = colv[i4 * 4 + 1] + rr.y;
        vals[i4 * 4 + 2] = colv[i4 * 4 + 2] + rr.z;
        vals[i4 * 4 + 3] = colv[i4 * 4 + 3] + rr.w;
      }
      #pragma unroll
      for (int i = 0; i < 32; i++) m = fmaxf(m, vals[i]);
      m = fmaxf(m, __shfl_xor(m, 1));
      m = fmaxf(m, __shfl_xor(m, 2));
      float s0 = 0.f, s1 = 0.f, s2 = 0.f, s3 = 0.f;
      #pragma unroll
      for (int i = 0; i < 8; i++) {
        s0 += __expf(vals[i * 4 + 0] - m);
        s1 += __expf(vals[i * 4 + 1] - m);
        s2 += __expf(vals[i * 4 + 2] - m);
        s3 += __expf(vals[i * 4 + 3] - m);
      }
      float ss = (s0 + s1) + (s2 + s3);
      ss += __shfl_xor(ss, 1);
      ss += __shfl_xor(ss, 2);
      if (qq == 0) ca[own] = -(m + logf(ss));
    }
    __syncthreads();
  }

  {
    float best = -1e30f; int bi = qq * 32;
    #pragma unroll
    for (int i = 0; i < 32; i++) {
      float val = rowv[i] + ca[qq * 32 + i];
      if (val > best) { best = val; bi = qq * 32 + i; }
    }
    #pragma unroll
    for (int d = 1; d < 4; d <<= 1) {
      float ob = __shfl_xor(best, d);
      int   oi = __shfl_xor(bi, d);
      if (ob > best || (ob == best && oi < bi)) { best = ob; bi = oi; }
    }
    if (qq == 0) {
      idxb[bh * NBUCK + own] = bi;
      sb[bh * NBUCK + own]   = expf(rl[own * 129 + bi] + ra[own] + ca[bi]);
    }
  }
}

// ---------------------------------------------------------------------------
// Kernel 4: per-bucket attention. grid (128,16), 256 threads (4 waves).
// 32 KB LDS. Region map (ushort indices):
//   [0,16384)  = K tile (128x128 bf16)  -- dead after B2
//   [0,8192)   = P tile (64x128 bf16)   -- written after B2
//   [8192,16384) = V half (128d x 64j)  -- written after B2 (V1), B4 (V2)
// V1 held in regs pre-B1 -> B2 (R2-proven); V2 load issued only after B2
// (saves ~32 VGPR vs R2). No min-waves bound (avoids R3 spill cascade).
// ---------------------------------------------------------------------------
__global__ __launch_bounds__(256) void k_attn(
    const float* __restrict__ q, const float* __restrict__ k, const float* __restrict__ v,
    const int* __restrict__ idxb, const float* __restrict__ sb, float* __restrict__ out) {
  const int u  = blockIdx.x;
  const int bh = blockIdx.y;
  const int t  = threadIdx.x;
  const int lane = t & 63;
  const int w  = t >> 6;
  const int l15 = lane & 15;
  const int lgp = lane >> 4;

  __shared__ uint4 smem4[2048];   // 32 KB
  unsigned short* sm = (unsigned short*)smem4;
  #define VOFF 8192

  const int   vidx = idxb[bh * NBUCK + u];
  const float sval = sb[bh * NBUCK + u];
  const size_t hb = (size_t)bh * (T_SEQ * DH);
  const float* qg = q + hb;
  const float* kg = k + hb;
  const float* vg = v + hb;

  // ---- K -> LDS (interleaved load/cvt/store; compiler pipelines) ----
  #pragma unroll
  for (int it = 0; it < 16; it++) {
    int i = it * 256 + t;
    int row = i >> 5;
    int c4 = (i & 31) << 2;
    int grow = (row < 64) ? (vidx * BSZ + row) : (u * BSZ + (row - 64));
    float4 val = *(const float4*)(kg + (size_t)grow * DH + c4);
    ushort4 hh;
    hh.x = f2bf(val.x); hh.y = f2bf(val.y); hh.z = f2bf(val.z); hh.w = f2bf(val.w);
    *(ushort4*)(sm + (((row * 128 + c4) ^ SWZ(row)))) = hh;
  }
  // ---- Q fragments direct global -> reg ----
  bf16x8 aQ[4];
  {
    int qrow = u * BSZ + w * 16 + l15;
    const float* qp = qg + (size_t)qrow * DH + lgp * 8;
    #pragma unroll
    for (int kk = 0; kk < 4; kk++) {
      float4 v0 = *(const float4*)(qp + kk * 32);
      float4 v1 = *(const float4*)(qp + kk * 32 + 4);
      bf16x8 f;
      f[0] = (__bf16)v0.x; f[1] = (__bf16)v0.y; f[2] = (__bf16)v0.z; f[3] = (__bf16)v0.w;
      f[4] = (__bf16)v1.x; f[5] = (__bf16)v1.y; f[6] = (__bf16)v1.z; f[7] = (__bf16)v1.w;
      aQ[kk] = f;
    }
  }
  // ---- issue V half-1 loads (held in regs until B2; region busy with K) ----
  float4 vpre1[8];
  #pragma unroll
  for (int it = 0; it < 8; it++) {
    int i = it * 256 + t;
    int d0 = (i & 31) << 2;
    int j  = i >> 5;
    vpre1[it] = *(const float4*)(vg + (size_t)(vidx * BSZ + j) * DH + d0);
  }
  __syncthreads();   // B1: K staged

  // ---- S = Q K^T ----
  f32x4 accS[8];
  __builtin_amdgcn_s_setprio(1);
  #pragma unroll
  for (int n = 0; n < 8; n++) {
    f32x4 acc = {0.f, 0.f, 0.f, 0.f};
    #pragma unroll
    for (int kk = 0; kk < 4; kk++) {
      int row = n * 16 + l15;
      int c0 = lgp * 8 + kk * 32;
      bf16x8 bK = *(const bf16x8*)(sm + ((row * 128 + c0) ^ SWZ(row)));
      acc = __builtin_amdgcn_mfma_f32_16x16x32_bf16(aQ[kk], bK, acc, 0, 0, 0);
    }
    accS[n] = acc;
  }
  __builtin_amdgcn_s_setprio(0);

  // ---- softmax per row ----
  float pval[8][4];
  float lsum[4];
  #pragma unroll
  for (int r = 0; r < 4; r++) {
    float mm = -1e30f;
    #pragma unroll
    for (int n = 0; n < 8; n++) {
      float lg2 = accS[n][r] * 0.03125f * (n < 4 ? sval : 1.0f);
      pval[n][r] = lg2;
      mm = fmaxf(mm, lg2);
    }
    mm = fmaxf(mm, __shfl_xor(mm, 1));
    mm = fmaxf(mm, __shfl_xor(mm, 2));
    mm = fmaxf(mm, __shfl_xor(mm, 4));
    mm = fmaxf(mm, __shfl_xor(mm, 8));
    float ss = 0.f;
    #pragma unroll
    for (int n = 0; n < 8; n++) {
      float p = __expf(pval[n][r] - mm);
      ss += p;
      pval[n][r] = p * (n < 4 ? sval : 1.0f);
    }
    ss += __shfl_xor(ss, 1);
    ss += __shfl_xor(ss, 2);
    ss += __shfl_xor(ss, 4);
    ss += __shfl_xor(ss, 8);
    lsum[r] = ss;
  }

  __syncthreads();   // B2: all waves done reading K; K region reusable

  // ---- write P (own wave rows) into [0,8192) ----
  #pragma unroll
  for (int n = 0; n < 8; n++) {
    #pragma unroll
    for (int r = 0; r < 4; r++) {
      int prow = w * 16 + lgp * 4 + r;
      int pcol = n * 16 + l15;
      sm[(prow * 128 + pcol) ^ SWZ(prow)] = f2bf(pval[n][r]);
    }
  }
  // ---- V half-1 regs -> LDS [8192,16384) ----
  #pragma unroll
  for (int it = 0; it < 8; it++) {
    int i = it * 256 + t;
    int d0 = (i & 31) << 2;
    int j  = i >> 5;
    float4 val = vpre1[it];
    sm[VOFF + (((d0 + 0) * 64 + j) ^ SWZ(d0 + 0))] = f2bf(val.x);
    sm[VOFF + (((d0 + 1) * 64 + j) ^ SWZ(d0 + 1))] = f2bf(val.y);
    sm[VOFF + (((d0 + 2) * 64 + j) ^ SWZ(d0 + 2))] = f2bf(val.z);
    sm[VOFF + (((d0 + 3) * 64 + j) ^ SWZ(d0 + 3))] = f2bf(val.w);
  }
  // ---- issue V half-2 loads (live only B2 -> B4; vpre1 is dead now) ----
  float4 vpre2[8];
  #pragma unroll
  for (int it = 0; it < 8; it++) {
    int i = it * 256 + t;
    int d0 = (i & 31) << 2;
    int j  = i >> 5;
    vpre2[it] = *(const float4*)(vg + (size_t)(u * BSZ + j) * DH + d0);
  }
  __syncthreads();   // B3: P + V1 ready

  // ---- aP fragments ----
  bf16x8 aP[4];
  #pragma unroll
  for (int kk = 0; kk < 4; kk++) {
    int prow = w * 16 + l15;
    int c0 = lgp * 8 + kk * 32;
    aP[kk] = *(const bf16x8*)(sm + ((prow * 128 + c0) ^ SWZ(prow)));
  }

  // ---- PV part 1 (j = 0..63) ----
  f32x4 accO[8];
  __builtin_amdgcn_s_setprio(1);
  #pragma unroll
  for (int n = 0; n < 8; n++) {
    f32x4 acc = {0.f, 0.f, 0.f, 0.f};
    #pragma unroll
    for (int kk = 0; kk < 2; kk++) {
      int d = n * 16 + l15;
      int jj0 = lgp * 8 + kk * 32;
      bf16x8 bV = *(const bf16x8*)(sm + VOFF + ((d * 64 + jj0) ^ SWZ(d)));
      acc = __builtin_amdgcn_mfma_f32_16x16x32_bf16(aP[kk], bV, acc, 0, 0, 0);
    }
    accO[n] = acc;
  }
  __builtin_amdgcn_s_setprio(0);
  __syncthreads();   // B4: done reading V1

  // ---- V half-2 regs -> LDS ----
  #pragma unroll
  for (int it = 0; it < 8; it++) {
    int i = it * 256 + t;
    int d0 = (i & 31) << 2;
    int j  = i >> 5;
    float4 val = vpre2[it];
    sm[VOFF + (((d0 + 0) * 64 + j) ^ SWZ(d0 + 0))] = f2bf(val.x);
    sm[VOFF + (((d0 + 1) * 64 + j) ^ SWZ(d0 + 1))] = f2bf(val.y);
    sm[VOFF + (((d0 + 2) * 64 + j) ^ SWZ(d0 + 2))] = f2bf(val.z);
    sm[VOFF + (((d0 + 3) * 64 + j) ^ SWZ(d0 + 3))] = f2bf(val.w);
  }
  __syncthreads();   // B5: V2 ready

  float invl[4];
  #pragma unroll
  for (int r = 0; r < 4; r++) invl[r] = 1.0f / lsum[r];

  // ---- PV part 2 (j = 64..127) + store ----
  __builtin_amdgcn_s_setprio(1);
  #pragma unroll
  for (int n = 0; n < 8; n++) {
    f32x4 acc = accO[n];
    #pragma unroll
    for (int kk = 2; kk < 4; kk++) {
      int d = n * 16 + l15;
      int jj0 = lgp * 8 + (kk - 2) * 32;
      bf16x8 bV = *(const bf16x8*)(sm + VOFF + ((d * 64 + jj0) ^ SWZ(d)));
      acc = __builtin_amdgcn_mfma_f32_16x16x32_bf16(aP[kk], bV, acc, 0, 0, 0);
    }
    #pragma unroll
    for (int r = 0; r < 4; r++) {
      int i2 = w * 16 + lgp * 4 + r;
      int d = n * 16 + l15;
      out[((size_t)bh * T_SEQ + (size_t)u * BSZ + i2) * DH + d] = acc[r] * invl[r];
    }
  }
  __builtin_amdgcn_s_setprio(0);
}

// ---------------------------------------------------------------------------
extern "C" void kernel_launch(void* const* d_in, const int* in_sizes, int n_in,
                              void* d_out, int out_size, void* d_ws, size_t ws_size,
                              hipStream_t stream) {
  (void)in_sizes; (void)n_in; (void)out_size; (void)ws_size;
  const float* q  = (const float*)d_in[0];
  const float* k  = (const float*)d_in[1];
  const float* v  = (const float*)d_in[2];
  const float* W  = (const float*)d_in[3];
  const float* ug = (const float*)d_in[4];
  float* out = (float*)d_out;

  float* xbuf = (float*)d_ws;                                  // 2 MB
  float* rbuf = xbuf + (size_t)NBH * NBUCK * 256;              // 1 MB
  int*   idxb = (int*)(rbuf + (size_t)NBH * NBUCK * NBUCK);
  float* sb   = (float*)(idxb + NBH * NBUCK);

  k_bsum    <<<dim3(NBUCK, NBH, 2), 256, 0, stream>>>(q, k, xbuf);
  k_sortgemm<<<dim3(32, NBH),       128, 0, stream>>>(xbuf, W, ug, rbuf);
  k_sinkhorn<<<NBH,                 512, 0, stream>>>(rbuf, idxb, sb);
  k_attn    <<<dim3(NBUCK, NBH),    256, 0, stream>>>(q, k, v, idxb, sb, out);
}